// Round 16
// baseline (43.371 us; speedup 1.0000x reference)
//
#include <hip/hip_runtime.h>
#include <hip/hip_bf16.h>
#include <math.h>

#define N_HALF 2048
#define M_TOT  4096
#define D_DIM  256
#define K2     512
#define NBLK   16            // M_TOT / 256 column blocks
#define NKT    16            // K2 / 32 k-tiles
#define A_TB   8192          // A K-tile: 128 rows x 32 k x 2 B (UNswizzled)
#define B_TB   16384         // B K-tile: 256 rows x 32 k x 2 B (swizzled)
#define BBUF   16384         // one LDS buffer: B only
#define NROWB  32            // M_TOT / 128 row blocks

typedef __attribute__((ext_vector_type(8))) short bf16x8;
typedef __attribute__((ext_vector_type(4))) float f32x4;

static __device__ __forceinline__ unsigned short f2bf(float x) {
    union { __hip_bfloat16 h; unsigned short u; } cv;
    cv.h = __float2bfloat16(x);
    return cv.u;
}

static __device__ __forceinline__ void gll16(const void* g, void* l) {
    __builtin_amdgcn_global_load_lds(
        (const __attribute__((address_space(1))) unsigned int*)g,
        (__attribute__((address_space(3))) unsigned int*)l, 16, 0, 0);
}

#define FENCE asm volatile("" ::: "memory")
#define BAR() do { FENCE; __builtin_amdgcn_s_barrier(); FENCE; } while (0)
#define VM(n) asm volatile("s_waitcnt vmcnt(" #n ")" ::: "memory")

// ---------------------------------------------------------------------------
// Kernel 1: bf16 operands + row scalars.
//   A[i] = [mu^2+var , -2*mu]  -> 32 row-blocks x 16 k-tiles of 8 KB, row-major
//          UNswizzled (read directly global->VGPR by the GEMM).
//   B[j] = [1/var , mu/var]    -> 16 col-blocks x 16 k-tiles of 16 KB, 16B
//          slots swizzled slot' = slot ^ ((r>>1)&3) (zero-conflict ds_read).
//   Block 0 also zeroes out[0] for finalize's atomicAdd.
// ---------------------------------------------------------------------------
__global__ __launch_bounds__(256) void prep_kernel(
        const float* __restrict__ loc1, const float* __restrict__ scale1,
        const float* __restrict__ loc2, const float* __restrict__ scale2,
        unsigned short* __restrict__ Ab, unsigned short* __restrict__ Bb,
        float* __restrict__ slv, float* __restrict__ cvec,
        float* __restrict__ out) {
    const int t = threadIdx.x, w = t >> 6, lane = t & 63;
    if (blockIdx.x == 0 && t == 0) out[0] = 0.0f;
    const int i = blockIdx.x * 4 + w;
    const float* mup  = (i < N_HALF) ? loc1 + (size_t)i * D_DIM   : loc2 + (size_t)(i - N_HALF) * D_DIM;
    const float* vap  = (i < N_HALF) ? scale1 + (size_t)i * D_DIM : scale2 + (size_t)(i - N_HALF) * D_DIM;
    const float4 mu = *(const float4*)(mup + lane * 4);
    const float4 va = *(const float4*)(vap + lane * 4);
    const float4 iv = {1.0f / va.x, 1.0f / va.y, 1.0f / va.z, 1.0f / va.w};

    float lacc = __logf(va.x * va.y * va.z * va.w);
    float cacc = mu.x * mu.x * iv.x + mu.y * mu.y * iv.y
               + mu.z * mu.z * iv.z + mu.w * mu.w * iv.w;
    #pragma unroll
    for (int off = 1; off < 64; off <<= 1) {
        lacc += __shfl_xor(lacc, off, 64);
        cacc += __shfl_xor(cacc, off, 64);
    }
    if (lane == 0) { slv[i] = lacc; cvec[i] = cacc; }

    const int rsw = (i >> 1) & 3;
    char* const abase = (char*)Ab + (size_t)(i >> 7) * (NKT * A_TB) + (i & 127) * 64;
    char* const bbase = (char*)Bb + (size_t)(i >> 8) * (NKT * B_TB) + (i & 255) * 64;
    // A: unswizzled; B: 16B-slot XOR swizzle
    #define ST4(base, TB, k, SWZ, v0, v1, v2, v3)                                    \
        {   const int kk = (k);                                                      \
            const int kt = kk >> 5;                                                  \
            const int sl = ((kk >> 3) & 3) ^ (SWZ), hf = (kk >> 2) & 1;              \
            ushort4 pk = {f2bf(v0), f2bf(v1), f2bf(v2), f2bf(v3)};                   \
            *(ushort4*)((base) + (size_t)kt * (TB) + sl * 16 + hf * 8) = pk; }
    ST4(abase, A_TB, lane * 4,       0,   mu.x * mu.x + va.x, mu.y * mu.y + va.y,
                                          mu.z * mu.z + va.z, mu.w * mu.w + va.w)
    ST4(abase, A_TB, 256 + lane * 4, 0,   -2.0f * mu.x, -2.0f * mu.y, -2.0f * mu.z, -2.0f * mu.w)
    ST4(bbase, B_TB, lane * 4,       rsw, iv.x, iv.y, iv.z, iv.w)
    ST4(bbase, B_TB, 256 + lane * 4, rsw, mu.x * iv.x, mu.y * iv.y, mu.z * iv.z, mu.w * iv.w)
    #undef ST4
}

// ---------------------------------------------------------------------------
// Kernel 2: bf16 MFMA GEMM, 128x256 tile, grid 512 (2 blocks/CU), 8 waves
// (2Mx4N, 64x64 wave tiles). A is read DIRECTLY global->VGPR (coalesced 1KB
// per 16-lane group, L2-resident via XCD chunking) — no LDS for A. B uses
// the proven swizzled gll16 path: 3 x 16KB rotation staged 2 tiles ahead.
// One barrier per K-tile; counted VM(2) (issue order makes the compiler's
// A-operand wait transitively guarantee B(kt+1) residency).
// Epilogue: sim' = 5*acc + colv (row term cancels in lse-pos), writes (m,s)
// per (row,colblock) + pos'[i] = sim'[i, i^2048].
// ---------------------------------------------------------------------------
__global__ __launch_bounds__(512, 4) void gemm_lse_kernel(
        const unsigned short* __restrict__ Ab, const unsigned short* __restrict__ Bb,
        const float* __restrict__ slv, const float* __restrict__ cvec,
        float* __restrict__ pm, float* __restrict__ ps,
        float* __restrict__ pos) {
    extern __shared__ __align__(16) char smem[];   // 49152 B: 3 x B 16K
    const int t = threadIdx.x;
    const int lane = t & 63, wid = t >> 6;
    const int bid = blockIdx.x;
    // bijective 8x8-chunk XCD swizzle: per-XCD set = 1MB A + 2MB B < 4MB L2
    const int xcd = bid & 7, idx = bid >> 3;
    const int by2 = (xcd >> 1) * 8 + (idx >> 3);     // 32 row-blks
    const int bx  = (xcd & 1) * 8 + (idx & 7);       // 16 col-blks
    const int wrow = wid >> 2, wcol = wid & 3;       // 2 x 4 wave grid, 64x64 tiles
    const int fr = lane & 15, g = lane >> 4;
    const int t16 = t * 16;

    // B LDS frag offsets: row*64 + ((slot ^ ((row>>1)&3))<<4)
    int b_off[4];
    #pragma unroll
    for (int fn = 0; fn < 4; ++fn) {
        const int row = wcol * 64 + fn * 16 + fr;
        b_off[fn] = row * 64 + ((g ^ ((row >> 1) & 3)) << 4);
    }

    f32x4 acc[4][4];
    #pragma unroll
    for (int i = 0; i < 4; ++i)
        #pragma unroll
        for (int j = 0; j < 4; ++j) acc[i][j] = (f32x4){0.f, 0.f, 0.f, 0.f};

    // per-lane A pointer: row = wrow*64 + fm*16 + fr, 16B slot g; fm via imm offset
    const char* aPtr = (const char*)Ab + (size_t)by2 * (NKT * A_TB)
                       + (wrow * 64 + fr) * 64 + g * 16;
    const char* gB = (const char*)Bb + (size_t)bx * (NKT * B_TB);

    // stage one B K-tile (16K: 2 gll16/thread) into buffer bidx
    #define STAGEB(ktile, bidx)                                                      \
        {   const char* _sB = gB + (size_t)(ktile) * B_TB;                           \
            char* _d = smem + (bidx) * BBUF;                                         \
            gll16(_sB + t16,        _d + t16);                                       \
            gll16(_sB + 8192 + t16, _d + 8192 + t16); }

    STAGEB(0, 0)
    STAGEB(1, 1)
    VM(2);            // tile 0 resident (tile 1's 2 loads in flight)
    BAR();

    int cur = 0;
    bf16x8 bfr[4], af[4];
    for (int kt = 0; kt < NKT; ++kt) {
        const char* bufc = smem + cur * BBUF;
        // A direct loads for this tile (issued AFTER last iter's B-stage)
        #pragma unroll
        for (int q = 0; q < 4; ++q) af[q] = *(const bf16x8*)(aPtr + q * 1024);
        #pragma unroll
        for (int q = 0; q < 4; ++q) bfr[q] = *(const bf16x8*)(bufc + b_off[q]);
        int stg = cur + 2; if (stg >= 3) stg -= 3;
        if (kt + 2 < NKT) STAGEB(kt + 2, stg)
        __builtin_amdgcn_s_setprio(1);
        #pragma unroll
        for (int fm = 0; fm < 4; ++fm) {
            acc[fm][0] = __builtin_amdgcn_mfma_f32_16x16x32_bf16(af[fm], bfr[0], acc[fm][0], 0, 0, 0);
            acc[fm][1] = __builtin_amdgcn_mfma_f32_16x16x32_bf16(af[fm], bfr[1], acc[fm][1], 0, 0, 0);
            acc[fm][2] = __builtin_amdgcn_mfma_f32_16x16x32_bf16(af[fm], bfr[2], acc[fm][2], 0, 0, 0);
            acc[fm][3] = __builtin_amdgcn_mfma_f32_16x16x32_bf16(af[fm], bfr[3], acc[fm][3], 0, 0, 0);
        }
        __builtin_amdgcn_s_setprio(0);
        VM(2);        // only B(kt+2) may remain in flight across the barrier
        BAR();        // publish kt+1's buffer; guards rotation reuse
        aPtr += A_TB;
        cur = (cur + 1 == 3) ? 0 : cur + 1;
    }
    #undef STAGEB

    // ---- fused LSE epilogue (sim' = 5*acc + colv; row term cancels) ----
    float colv[4]; int gcol[4];
    #pragma unroll
    for (int fn = 0; fn < 4; ++fn) {
        const int c = bx * 256 + wcol * 64 + fn * 16 + fr;
        gcol[fn] = c;
        colv[fn] = 5.0f * (slv[c] + cvec[c]) - 1280.0f;   // 5*(slv+cvec-256)
    }
    float* redm = (float*)smem;             // [128][4]
    float* reds = (float*)(smem + 2048);    // [128][4]

    #pragma unroll
    for (int fm = 0; fm < 4; ++fm) {
        #pragma unroll
        for (int q = 0; q < 4; ++q) {
            const int rloc = wrow * 64 + fm * 16 + g * 4 + q;
            const int grow = by2 * 128 + rloc;
            const int jpart = grow ^ N_HALF;
            float v[4];
            #pragma unroll
            for (int fn = 0; fn < 4; ++fn) {
                const float x = 5.0f * acc[fm][fn][q] + colv[fn];
                if (gcol[fn] == jpart) pos[grow] = x;      // sim'[i, partner(i)]
                v[fn] = (grow == gcol[fn]) ? -3.0e38f : x;
            }
            float m = fmaxf(fmaxf(v[0], v[1]), fmaxf(v[2], v[3]));
            #pragma unroll
            for (int off = 1; off < 16; off <<= 1) m = fmaxf(m, __shfl_xor(m, off, 64));
            float s = __expf(v[0] - m) + __expf(v[1] - m) + __expf(v[2] - m) + __expf(v[3] - m);
            #pragma unroll
            for (int off = 1; off < 16; off <<= 1) s += __shfl_xor(s, off, 64);
            if (fr == 0) { redm[rloc * 4 + wcol] = m; reds[rloc * 4 + wcol] = s; }
        }
    }
    __syncthreads();
    if (t < 128) {
        float m = redm[t * 4], s = reds[t * 4];
        #pragma unroll
        for (int k = 1; k < 4; ++k) {
            const float mk = redm[t * 4 + k], sk = reds[t * 4 + k];
            const float nm = fmaxf(m, mk);
            s = s * __expf(m - nm) + sk * __expf(mk - nm);
            m = nm;
        }
        pm[(size_t)(by2 * 128 + t) * NBLK + bx] = m;
        ps[(size_t)(by2 * 128 + t) * NBLK + bx] = s;
    }
}

// ---------------------------------------------------------------------------
// Kernel 3: finalize + mean. 16 blocks x 256 threads, one row per thread:
// combine 16 (m,s) partials -> lse'; loss = lse' - pos' (row term cancels);
// block-reduce; one atomicAdd per block into out[0] (zeroed by prep).
// ---------------------------------------------------------------------------
__global__ __launch_bounds__(256) void finalize_kernel(
        const float* __restrict__ pm, const float* __restrict__ ps,
        const float* __restrict__ pos, float* __restrict__ out) {
    __shared__ float sm[256];
    const int t = threadIdx.x;
    const int i = blockIdx.x * 256 + t;
    float mk[NBLK];
    float m = -3.0e38f;
    #pragma unroll
    for (int k = 0; k < NBLK; ++k) {
        mk[k] = pm[(size_t)i * NBLK + k];
        m = fmaxf(m, mk[k]);
    }
    float s = 0.0f;
    #pragma unroll
    for (int k = 0; k < NBLK; ++k)
        s += ps[(size_t)i * NBLK + k] * __expf(mk[k] - m);
    sm[t] = m + logf(s) - pos[i];
    __syncthreads();
    for (int off = 128; off > 0; off >>= 1) {
        if (t < off) sm[t] += sm[t + off];
        __syncthreads();
    }
    if (t == 0) atomicAdd(out, sm[0] * (1.0f / (float)M_TOT));
}

// ---------------------------------------------------------------------------
extern "C" void kernel_launch(void* const* d_in, const int* in_sizes, int n_in,
                              void* d_out, int out_size, void* d_ws, size_t ws_size,
                              hipStream_t stream) {
    const float* loc1   = (const float*)d_in[0];
    const float* scale1 = (const float*)d_in[1];
    const float* loc2   = (const float*)d_in[2];
    const float* scale2 = (const float*)d_in[3];
    float* out = (float*)d_out;

    char* ws = (char*)d_ws;
    unsigned short* Ab = (unsigned short*)ws;                              // 4 MB
    unsigned short* Bb = (unsigned short*)(ws + (size_t)4 * 1024 * 1024);  // 4 MB
    float* slv  = (float*)(ws + (size_t)8 * 1024 * 1024);                  // 16 KB
    float* cvec = slv + M_TOT;
    float* pm   = cvec + M_TOT;                                            // 256 KB
    float* ps   = pm + (size_t)M_TOT * NBLK;                               // 256 KB
    float* pos  = ps + (size_t)M_TOT * NBLK;                               // 16 KB

    hipLaunchKernelGGL(prep_kernel, dim3(M_TOT / 4), dim3(256), 0, stream,
                       loc1, scale1, loc2, scale2, Ab, Bb, slv, cvec, out);
    hipLaunchKernelGGL(gemm_lse_kernel, dim3(NROWB * NBLK), dim3(512), 49152, stream,
                       Ab, Bb, slv, cvec, pm, ps, pos);
    hipLaunchKernelGGL(finalize_kernel, dim3(NBLK), dim3(256), 0, stream,
                       pm, ps, pos, out);
}

// Round 17
// 38.371 us; speedup vs baseline: 1.1303x; 1.1303x over previous
//
#include <hip/hip_runtime.h>
#include <hip/hip_bf16.h>
#include <math.h>

#define N_HALF 2048
#define M_TOT  4096
#define D_DIM  256
#define K2     512
#define NBLK   16            // M_TOT / 256 column blocks
#define NKT    16            // K2 / 32 k-tiles
#define A_TB   8192          // A K-tile: 128 rows x 32 k x 2 B
#define B_TB   16384         // B K-tile: 256 rows x 32 k x 2 B
#define BUF_B  24576         // one LDS buffer: A 8K + B 16K
#define NROWB  32            // M_TOT / 128 row blocks

typedef __attribute__((ext_vector_type(8))) short bf16x8;
typedef __attribute__((ext_vector_type(4))) float f32x4;

static __device__ __forceinline__ unsigned short f2bf(float x) {
    union { __hip_bfloat16 h; unsigned short u; } cv;
    cv.h = __float2bfloat16(x);
    return cv.u;
}

static __device__ __forceinline__ void gll16(const void* g, void* l) {
    __builtin_amdgcn_global_load_lds(
        (const __attribute__((address_space(1))) unsigned int*)g,
        (__attribute__((address_space(3))) unsigned int*)l, 16, 0, 0);
}

#define FENCE asm volatile("" ::: "memory")
#define BAR() do { FENCE; __builtin_amdgcn_s_barrier(); FENCE; } while (0)
#define VM(n) asm volatile("s_waitcnt vmcnt(" #n ")" ::: "memory")

// ---------------------------------------------------------------------------
// Kernel 1: bf16 operands, pre-swizzled K-tiles + row scalars.
//   A[i] = [mu^2+var , -2*mu]  -> 32 row-blocks of 128 rows, 16 tiles of 8 KB
//   B[j] = [1/var , mu/var]    -> 16 col-blocks of 256 rows, 16 tiles of 16 KB
//   Within a tile row r holds 64 B; 16B slots swizzled slot' = slot^((r>>1)&3)
//   so a linear global_load_lds yields the swizzled LDS image.
//   Block 0 also zeroes out[0] for finalize's atomicAdd.
// ---------------------------------------------------------------------------
__global__ __launch_bounds__(256) void prep_kernel(
        const float* __restrict__ loc1, const float* __restrict__ scale1,
        const float* __restrict__ loc2, const float* __restrict__ scale2,
        unsigned short* __restrict__ Ab, unsigned short* __restrict__ Bb,
        float* __restrict__ slv, float* __restrict__ cvec,
        float* __restrict__ out) {
    const int t = threadIdx.x, w = t >> 6, lane = t & 63;
    if (blockIdx.x == 0 && t == 0) out[0] = 0.0f;
    const int i = blockIdx.x * 4 + w;
    const float* mup  = (i < N_HALF) ? loc1 + (size_t)i * D_DIM   : loc2 + (size_t)(i - N_HALF) * D_DIM;
    const float* vap  = (i < N_HALF) ? scale1 + (size_t)i * D_DIM : scale2 + (size_t)(i - N_HALF) * D_DIM;
    const float4 mu = *(const float4*)(mup + lane * 4);
    const float4 va = *(const float4*)(vap + lane * 4);
    const float4 iv = {1.0f / va.x, 1.0f / va.y, 1.0f / va.z, 1.0f / va.w};

    float lacc = __logf(va.x * va.y * va.z * va.w);
    float cacc = mu.x * mu.x * iv.x + mu.y * mu.y * iv.y
               + mu.z * mu.z * iv.z + mu.w * mu.w * iv.w;
    #pragma unroll
    for (int off = 1; off < 64; off <<= 1) {
        lacc += __shfl_xor(lacc, off, 64);
        cacc += __shfl_xor(cacc, off, 64);
    }
    if (lane == 0) { slv[i] = lacc; cvec[i] = cacc; }

    const int rsw = (i >> 1) & 3;
    char* const abase = (char*)Ab + (size_t)(i >> 7) * (NKT * A_TB) + (i & 127) * 64;
    char* const bbase = (char*)Bb + (size_t)(i >> 8) * (NKT * B_TB) + (i & 255) * 64;
    #define ST4(base, TB, k, v0, v1, v2, v3)                                         \
        {   const int kk = (k);                                                      \
            const int kt = kk >> 5;                                                  \
            const int sl = ((kk >> 3) & 3) ^ rsw, hf = (kk >> 2) & 1;                \
            ushort4 pk = {f2bf(v0), f2bf(v1), f2bf(v2), f2bf(v3)};                   \
            *(ushort4*)((base) + (size_t)kt * (TB) + sl * 16 + hf * 8) = pk; }
    ST4(abase, A_TB, lane * 4,       mu.x * mu.x + va.x, mu.y * mu.y + va.y,
                                     mu.z * mu.z + va.z, mu.w * mu.w + va.w)
    ST4(abase, A_TB, 256 + lane * 4, -2.0f * mu.x, -2.0f * mu.y, -2.0f * mu.z, -2.0f * mu.w)
    ST4(bbase, B_TB, lane * 4,       iv.x, iv.y, iv.z, iv.w)
    ST4(bbase, B_TB, 256 + lane * 4, mu.x * iv.x, mu.y * iv.y, mu.z * iv.z, mu.w * iv.w)
    #undef ST4
}

// ---------------------------------------------------------------------------
// Kernel 2: bf16 MFMA GEMM, 128x256 tile, grid 512 (= 2 blocks/CU, LDS 72 KB),
// 8 waves (2Mx4N, wave tile 64x64), BK=32, 3-buffer rotation staged 2 tiles
// ahead, one barrier + counted VM(3) per K-tile. XCD-bijective block swizzle.
// Epilogue: sim' = 5*acc + colv (row term cancels in lse-pos), writes (m,s)
// per (row,colblock) + pos'[i] = sim'[i, i^2048].
// ---------------------------------------------------------------------------
__global__ __launch_bounds__(512, 4) void gemm_lse_kernel(
        const unsigned short* __restrict__ Ab, const unsigned short* __restrict__ Bb,
        const float* __restrict__ slv, const float* __restrict__ cvec,
        float* __restrict__ pm, float* __restrict__ ps,
        float* __restrict__ pos) {
    extern __shared__ __align__(16) char smem[];   // 73728 B: 3 x (A 8K | B 16K)
    const int t = threadIdx.x;
    const int lane = t & 63, wid = t >> 6;
    const int bid = blockIdx.x;
    const int swz = ((bid & 7) << 6) | (bid >> 3);   // 64-block chunk per XCD
    const int bx = swz >> 5, by2 = swz & 31;         // bx: 16 col-blks, by2: 32 row-blks
    const int wrow = wid >> 2, wcol = wid & 3;       // 2 x 4 wave grid, 64x64 tiles
    const int fr = lane & 15, g = lane >> 4;
    const int t16 = t * 16;

    // LDS frag offsets: row*64 + ((slot ^ ((row>>1)&3))<<4); B region at +8192
    int a_off[4], b_off[4];
    #pragma unroll
    for (int fm = 0; fm < 4; ++fm) {
        const int row = wrow * 64 + fm * 16 + fr;
        a_off[fm] = row * 64 + ((g ^ ((row >> 1) & 3)) << 4);
    }
    #pragma unroll
    for (int fn = 0; fn < 4; ++fn) {
        const int row = wcol * 64 + fn * 16 + fr;
        b_off[fn] = 8192 + row * 64 + ((g ^ ((row >> 1) & 3)) << 4);
    }

    f32x4 acc[4][4];
    #pragma unroll
    for (int i = 0; i < 4; ++i)
        #pragma unroll
        for (int j = 0; j < 4; ++j) acc[i][j] = (f32x4){0.f, 0.f, 0.f, 0.f};

    const char* gA = (const char*)Ab + (size_t)by2 * (NKT * A_TB);
    const char* gB = (const char*)Bb + (size_t)bx * (NKT * B_TB);

    // stage one K-tile (A 8K: 1 gll16; B 16K: 2 gll16) into buffer bidx
    #define STAGE(ktile, bidx)                                                       \
        {   const char* _sA = gA + (size_t)(ktile) * A_TB;                           \
            const char* _sB = gB + (size_t)(ktile) * B_TB;                           \
            char* _d = smem + (bidx) * BUF_B;                                        \
            gll16(_sA + t16,        _d + t16);                                       \
            gll16(_sB + t16,        _d + 8192 + t16);                                \
            gll16(_sB + 8192 + t16, _d + 16384 + t16); }

    STAGE(0, 0)
    STAGE(1, 1)
    VM(3);            // tile 0 resident (tile 1's 3 loads in flight)
    BAR();

    int cur = 0;
    bf16x8 bfr[4], af[4];
    for (int kt = 0; kt < NKT; ++kt) {
        const char* bufc = smem + cur * BUF_B;
        int stg = cur + 2; if (stg >= 3) stg -= 3;
        if (kt + 2 < NKT) STAGE(kt + 2, stg)
        #pragma unroll
        for (int q = 0; q < 4; ++q) bfr[q] = *(const bf16x8*)(bufc + b_off[q]);
        #pragma unroll
        for (int q = 0; q < 4; ++q) af[q]  = *(const bf16x8*)(bufc + a_off[q]);
        __builtin_amdgcn_s_setprio(1);
        #pragma unroll
        for (int fm = 0; fm < 4; ++fm) {
            acc[fm][0] = __builtin_amdgcn_mfma_f32_16x16x32_bf16(af[fm], bfr[0], acc[fm][0], 0, 0, 0);
            acc[fm][1] = __builtin_amdgcn_mfma_f32_16x16x32_bf16(af[fm], bfr[1], acc[fm][1], 0, 0, 0);
            acc[fm][2] = __builtin_amdgcn_mfma_f32_16x16x32_bf16(af[fm], bfr[2], acc[fm][2], 0, 0, 0);
            acc[fm][3] = __builtin_amdgcn_mfma_f32_16x16x32_bf16(af[fm], bfr[3], acc[fm][3], 0, 0, 0);
        }
        __builtin_amdgcn_s_setprio(0);
        if (kt + 2 < NKT)       { VM(3); }   // tile kt+1 resident (kt+2 in flight)
        else if (kt == NKT - 2) { VM(0); }   // last tile resident
        BAR();                               // publish; also guards buffer reuse
        cur = (cur + 1 == 3) ? 0 : cur + 1;
    }
    #undef STAGE

    // ---- fused LSE epilogue (sim' = 5*acc + colv; row term cancels) ----
    float colv[4]; int gcol[4];
    #pragma unroll
    for (int fn = 0; fn < 4; ++fn) {
        const int c = bx * 256 + wcol * 64 + fn * 16 + fr;
        gcol[fn] = c;
        colv[fn] = 5.0f * (slv[c] + cvec[c]) - 1280.0f;   // 5*(slv+cvec-256)
    }
    float* redm = (float*)smem;             // [128][4]
    float* reds = (float*)(smem + 2048);    // [128][4]

    #pragma unroll
    for (int fm = 0; fm < 4; ++fm) {
        #pragma unroll
        for (int q = 0; q < 4; ++q) {
            const int rloc = wrow * 64 + fm * 16 + g * 4 + q;
            const int grow = by2 * 128 + rloc;
            const int jpart = grow ^ N_HALF;
            float v[4];
            #pragma unroll
            for (int fn = 0; fn < 4; ++fn) {
                const float x = 5.0f * acc[fm][fn][q] + colv[fn];
                if (gcol[fn] == jpart) pos[grow] = x;      // sim'[i, partner(i)]
                v[fn] = (grow == gcol[fn]) ? -3.0e38f : x;
            }
            float m = fmaxf(fmaxf(v[0], v[1]), fmaxf(v[2], v[3]));
            #pragma unroll
            for (int off = 1; off < 16; off <<= 1) m = fmaxf(m, __shfl_xor(m, off, 64));
            float s = __expf(v[0] - m) + __expf(v[1] - m) + __expf(v[2] - m) + __expf(v[3] - m);
            #pragma unroll
            for (int off = 1; off < 16; off <<= 1) s += __shfl_xor(s, off, 64);
            if (fr == 0) { redm[rloc * 4 + wcol] = m; reds[rloc * 4 + wcol] = s; }
        }
    }
    __syncthreads();
    if (t < 128) {
        float m = redm[t * 4], s = reds[t * 4];
        #pragma unroll
        for (int k = 1; k < 4; ++k) {
            const float mk = redm[t * 4 + k], sk = reds[t * 4 + k];
            const float nm = fmaxf(m, mk);
            s = s * __expf(m - nm) + sk * __expf(mk - nm);
            m = nm;
        }
        pm[(size_t)(by2 * 128 + t) * NBLK + bx] = m;
        ps[(size_t)(by2 * 128 + t) * NBLK + bx] = s;
    }
}

// ---------------------------------------------------------------------------
// Kernel 3: finalize + mean. 16 blocks x 256 threads, one row per thread:
// combine 16 (m,s) partials -> lse'; loss = lse' - pos' (row term cancels);
// block-reduce; one atomicAdd per block into out[0] (zeroed by prep).
// ---------------------------------------------------------------------------
__global__ __launch_bounds__(256) void finalize_kernel(
        const float* __restrict__ pm, const float* __restrict__ ps,
        const float* __restrict__ pos, float* __restrict__ out) {
    __shared__ float sm[256];
    const int t = threadIdx.x;
    const int i = blockIdx.x * 256 + t;
    float mk[NBLK];
    float m = -3.0e38f;
    #pragma unroll
    for (int k = 0; k < NBLK; ++k) {
        mk[k] = pm[(size_t)i * NBLK + k];
        m = fmaxf(m, mk[k]);
    }
    float s = 0.0f;
    #pragma unroll
    for (int k = 0; k < NBLK; ++k)
        s += ps[(size_t)i * NBLK + k] * __expf(mk[k] - m);
    sm[t] = m + logf(s) - pos[i];
    __syncthreads();
    for (int off = 128; off > 0; off >>= 1) {
        if (t < off) sm[t] += sm[t + off];
        __syncthreads();
    }
    if (t == 0) atomicAdd(out, sm[0] * (1.0f / (float)M_TOT));
}

// ---------------------------------------------------------------------------
extern "C" void kernel_launch(void* const* d_in, const int* in_sizes, int n_in,
                              void* d_out, int out_size, void* d_ws, size_t ws_size,
                              hipStream_t stream) {
    const float* loc1   = (const float*)d_in[0];
    const float* scale1 = (const float*)d_in[1];
    const float* loc2   = (const float*)d_in[2];
    const float* scale2 = (const float*)d_in[3];
    float* out = (float*)d_out;

    char* ws = (char*)d_ws;
    unsigned short* Ab = (unsigned short*)ws;                              // 4 MB
    unsigned short* Bb = (unsigned short*)(ws + (size_t)4 * 1024 * 1024);  // 4 MB
    float* slv  = (float*)(ws + (size_t)8 * 1024 * 1024);                  // 16 KB
    float* cvec = slv + M_TOT;
    float* pm   = cvec + M_TOT;                                            // 256 KB
    float* ps   = pm + (size_t)M_TOT * NBLK;                               // 256 KB
    float* pos  = ps + (size_t)M_TOT * NBLK;                               // 16 KB

    hipLaunchKernelGGL(prep_kernel, dim3(M_TOT / 4), dim3(256), 0, stream,
                       loc1, scale1, loc2, scale2, Ab, Bb, slv, cvec, out);
    hipLaunchKernelGGL(gemm_lse_kernel, dim3(NROWB * NBLK), dim3(512), 73728, stream,
                       Ab, Bb, slv, cvec, pm, ps, pos);
    hipLaunchKernelGGL(finalize_kernel, dim3(NBLK), dim3(256), 0, stream,
                       pm, ps, pos, out);
}